// Round 1
// baseline (1043.203 us; speedup 1.0000x reference)
//
#include <hip/hip_runtime.h>
#include <stdint.h>

// MLA decode: B=32, H=32, KV_LORA=512, ROPE=64, NOPE=128, VH=128, QL=1536,
// HID=5120, BLK=128, 32 blocks/seq, NB=1024. fp32 in/out, bf16 MFMA internals.

typedef __attribute__((ext_vector_type(8))) short short8;
typedef __attribute__((ext_vector_type(4))) float f32x4;

__device__ inline uint32_t f2bf(float f) {
  uint32_t u = __float_as_uint(f);
  return (u + 0x7fffu + ((u >> 16) & 1u)) >> 16;   // RNE
}
__device__ inline uint32_t pack2bf(float lo, float hi) {
  return f2bf(lo) | (f2bf(hi) << 16);
}
union FragU { uint32_t u[4]; short8 s; };
__device__ inline short8 frag_from(const uint32_t r[4]) {
  FragU v; v.u[0] = r[0]; v.u[1] = r[1]; v.u[2] = r[2]; v.u[3] = r[3];
  return v.s;
}

// ---------------------------------------------------------------- K1: q proj
// out[b][c] = sum_k hidden[b][k] * W[k][c], W = [W_Q (4096 cols) | W_QR (2048)]
// grid (96 col-tiles of 64, 2 k-halves), atomicAdd into zeroed q_nope0/q_pe0.
__global__ __launch_bounds__(256) void k1_qproj(
    const float* __restrict__ hidden, const float* __restrict__ W_Q,
    const float* __restrict__ W_QR, float* __restrict__ q_nope0,
    float* __restrict__ q_pe0) {
  __shared__ float hl[32][128];
  const int t = threadIdx.x;
  const int ctile = blockIdx.x * 64;
  const int khalf = blockIdx.y;
  const int cl = t & 63, bg = t >> 6;   // 4 groups x 8 batch rows
  const int c = ctile + cl;
  const bool isQ = (c < 4096);
  const float* W = isQ ? W_Q : W_QR;
  const int wstride = isQ ? 4096 : 2048;
  const int wc = isQ ? c : (c - 4096);
  float acc[8] = {0, 0, 0, 0, 0, 0, 0, 0};
  for (int kc = 0; kc < 6; ++kc) {
    const int k0 = khalf * 768 + kc * 128;
    __syncthreads();
    for (int idx = t; idx < 4096; idx += 256) {
      int b = idx >> 7, kk = idx & 127;
      hl[b][kk] = hidden[b * 1536 + k0 + kk];
    }
    __syncthreads();
    for (int kk = 0; kk < 128; ++kk) {
      float w = W[(k0 + kk) * wstride + wc];
#pragma unroll
      for (int r = 0; r < 8; ++r) acc[r] += hl[bg * 8 + r][kk] * w;
    }
  }
  float* dst = isQ ? q_nope0 : q_pe0;
  for (int r = 0; r < 8; ++r)
    atomicAdd(&dst[(bg * 8 + r) * wstride + wc], acc[r]);
}

// --------------------------------------------------------------- K2: q_lora
// q_bf[b][h][c] = bf16( scale * sum_d q_nope0[b][h*128+d] * W_UK[h][d][c] )
__global__ __launch_bounds__(256) void k2_qlora(
    const float* __restrict__ q_nope0, const float* __restrict__ W_UK,
    uint16_t* __restrict__ q_bf) {
  __shared__ float qn[32][128];
  const int t = threadIdx.x;
  const int h = blockIdx.y;
  const int c0 = blockIdx.x * 128;
  for (int idx = t; idx < 4096; idx += 256) {
    int b = idx >> 7, d = idx & 127;
    qn[b][d] = q_nope0[b * 4096 + h * 128 + d];
  }
  __syncthreads();
  const int cl = t & 127, rg = t >> 7;
  const float scale = 0.07216878364870323f;  // 1/sqrt(192)
  float acc[16];
#pragma unroll
  for (int r = 0; r < 16; ++r) acc[r] = 0.f;
  for (int d = 0; d < 128; ++d) {
    float w = W_UK[(h * 128 + d) * 512 + c0 + cl];
#pragma unroll
    for (int r = 0; r < 16; ++r) acc[r] += qn[rg * 16 + r][d] * w;
  }
  for (int r = 0; r < 16; ++r) {
    int b = rg * 16 + r;
    q_bf[(b * 32 + h) * 576 + c0 + cl] = (uint16_t)f2bf(acc[r] * scale);
  }
}

// ---------------------------------------------- K2b: RoPE + cache scatter
__global__ __launch_bounds__(256) void k2b_rope_scatter(
    const float* __restrict__ q_pe0, const float* __restrict__ k_pe,
    const float* __restrict__ k_c_normed, const int* __restrict__ ipos,
    const int* __restrict__ bindices, const int* __restrict__ boffsets,
    float* __restrict__ cache_k, float* __restrict__ cache_v,
    uint16_t* __restrict__ q_bf) {
  const int b = blockIdx.x;
  const int t = threadIdx.x;
  const float pos = (float)ipos[b];
  const float scale = 0.07216878364870323f;
  const float lnk = 0.28782313662425575f;  // ln(10000)/32
  for (int idx = t; idx < 1024; idx += 256) {
    int h = idx >> 5, i = idx & 31;
    float ang = pos * __expf(-(float)i * lnk);
    float s, c; sincosf(ang, &s, &c);
    float x1 = q_pe0[b * 2048 + h * 64 + i];
    float x2 = q_pe0[b * 2048 + h * 64 + 32 + i];
    int base = (b * 32 + h) * 576 + 512;
    q_bf[base + i]      = (uint16_t)f2bf((x1 * c - x2 * s) * scale);
    q_bf[base + 32 + i] = (uint16_t)f2bf((x2 * c + x1 * s) * scale);
  }
  const int row = bindices[b] * 128 + boffsets[b];
  if (t < 32) {
    int i = t;
    float ang = pos * __expf(-(float)i * lnk);
    float s, c; sincosf(ang, &s, &c);
    float x1 = k_pe[b * 64 + i], x2 = k_pe[b * 64 + 32 + i];
    cache_k[row * 64 + i]      = x1 * c - x2 * s;
    cache_k[row * 64 + 32 + i] = x2 * c + x1 * s;
  }
  for (int j = t; j < 512; j += 256)
    cache_v[row * 512 + j] = k_c_normed[b * 512 + j];
}

// ------------------------------------------------------------ K3: attention
// grid (16 parts, 32 seqs), 256 thr (4 waves), 2 blocks/WG, 32-kv sub-tiles.
// LDS tile Tl: d-pair-zip  Tl[d2*33+kv] = {T[kv][2d2], T[kv][2d2+1]} (bf16 pair)
// Logits B-frag = direct b32 reads; PV B-frag = 8x b32 + 16-bit extract.
__global__ __launch_bounds__(256, 2) void k3_attn(
    const uint16_t* __restrict__ q_bf, const float* __restrict__ cache_k,
    const float* __restrict__ cache_v, const int* __restrict__ block_list,
    const int* __restrict__ block_groups, const float* __restrict__ block_bias,
    float* __restrict__ num_part, float* __restrict__ den_part) {
  __shared__ uint32_t Tl[288 * 33];
  __shared__ uint32_t Pl[16 * 33];
  __shared__ float den_sh[2][32];

  const int t = threadIdx.x;
  const int part = blockIdx.x, bseq = blockIdx.y;
  const int wg = bseq * 16 + part;
  const int wave = t >> 6, lane = t & 63, quad = lane >> 4, l16 = lane & 15;
  const int hh = wave >> 1, kvh = wave & 1;
  const int n0 = bseq * 32 + part * 2;
  const int g = block_groups[n0];

  // Q fragments (this wave's 16-head half), 72 dwords in registers
  uint32_t qf[72];
  {
    const uint32_t* qrow =
        (const uint32_t*)(q_bf + (size_t)(g * 32 + hh * 16 + l16) * 576);
#pragma unroll
    for (int ks = 0; ks < 18; ++ks)
#pragma unroll
      for (int i = 0; i < 4; ++i)
        qf[ks * 4 + i] = qrow[ks * 16 + quad * 4 + i];
  }

  const f32x4 fzero = {0.f, 0.f, 0.f, 0.f};
  f32x4 acc[2][8];
#pragma unroll
  for (int mt = 0; mt < 2; ++mt)
#pragma unroll
    for (int nt = 0; nt < 8; ++nt) acc[mt][nt] = fzero;
  float den_acc[4] = {0.f, 0.f, 0.f, 0.f};

  for (int blk_i = 0; blk_i < 2; ++blk_i) {
    const int n = n0 + blk_i;
    const int phys = block_list[n];
    const float* vrow = cache_v + (size_t)phys * 128 * 512;
    const float* krow = cache_k + (size_t)phys * 128 * 64;
    for (int s = 0; s < 4; ++s) {
      const int s0 = s * 32;
      __syncthreads();  // previous PV readers done
      for (int idx = t; idx < 4608; idx += 256) {   // 32 kv x 144 float4
        int kv = idx / 144, f4 = idx - kv * 144;
        float4 v; int d0;
        if (f4 < 128) { v = *(const float4*)(vrow + (s0 + kv) * 512 + f4 * 4); d0 = f4 * 4; }
        else { v = *(const float4*)(krow + (s0 + kv) * 64 + (f4 - 128) * 4); d0 = 512 + (f4 - 128) * 4; }
        int d2 = d0 >> 1;
        Tl[(d2    ) * 33 + kv] = pack2bf(v.x, v.y);
        Tl[(d2 + 1) * 33 + kv] = pack2bf(v.z, v.w);
      }
      __syncthreads();
      // ---- logits: wave computes 16h x 16kv tile (hh, kvh), K = 576
      const int tkv = kvh * 16 + l16;
      f32x4 lg = fzero;
#pragma unroll
      for (int ks = 0; ks < 18; ++ks) {
        uint32_t br[4];
#pragma unroll
        for (int i = 0; i < 4; ++i)
          br[i] = Tl[(ks * 16 + quad * 4 + i) * 33 + tkv];
        lg = __builtin_amdgcn_mfma_f32_16x16x32_bf16(
            frag_from(&qf[ks * 4]), frag_from(br), lg, 0, 0, 0);
      }
      float bias = block_bias[n * 128 + s0 + tkv];
      uint32_t pb[4];
#pragma unroll
      for (int r = 0; r < 4; ++r) {
        float p = __expf(lg[r] + bias);   // no shift: |logit| <= ~9, safe
        pb[r] = f2bf(p);
        den_acc[r] += __uint_as_float(pb[r] << 16);
      }
#pragma unroll
      for (int r = 0; r < 4; ++r) {       // kv-pair-zip P into LDS
        uint32_t other = (uint32_t)__shfl_xor((int)pb[r], 1, 64);
        if ((l16 & 1) == 0) {
          int h = hh * 16 + quad * 4 + r;
          Pl[(tkv >> 1) * 33 + h] = pb[r] | (other << 16);
        }
      }
      __syncthreads();
      // ---- PV: wave handles l-slice [wave*128, wave*128+128)
      uint32_t af[2][4];
#pragma unroll
      for (int mt = 0; mt < 2; ++mt)
#pragma unroll
        for (int i = 0; i < 4; ++i)
          af[mt][i] = Pl[(quad * 4 + i) * 33 + mt * 16 + l16];
#pragma unroll
      for (int nt = 0; nt < 8; ++nt) {
        int l = wave * 128 + nt * 16 + l16;
        const uint32_t* base = &Tl[(l >> 1) * 33 + quad * 8];
        uint32_t dw[8];
#pragma unroll
        for (int j = 0; j < 8; ++j) dw[j] = base[j];
        uint32_t br[4];
        const bool odd = (l & 1);
#pragma unroll
        for (int i = 0; i < 4; ++i) {
          uint32_t a = dw[2 * i], bq = dw[2 * i + 1];
          uint32_t lo = odd ? (a >> 16) : (a & 0xffffu);
          uint32_t hi = odd ? (bq & 0xffff0000u) : (bq << 16);
          br[i] = lo | hi;
        }
        short8 bf = frag_from(br);
        acc[0][nt] = __builtin_amdgcn_mfma_f32_16x16x32_bf16(
            frag_from(af[0]), bf, acc[0][nt], 0, 0, 0);
        acc[1][nt] = __builtin_amdgcn_mfma_f32_16x16x32_bf16(
            frag_from(af[1]), bf, acc[1][nt], 0, 0, 0);
      }
    }
  }
  // write num partial (coalesced over l16)
#pragma unroll
  for (int mt = 0; mt < 2; ++mt)
#pragma unroll
    for (int nt = 0; nt < 8; ++nt)
#pragma unroll
      for (int r = 0; r < 4; ++r) {
        int h = mt * 16 + quad * 4 + r;
        int l = wave * 128 + nt * 16 + l16;
        num_part[((size_t)wg * 32 + h) * 512 + l] = acc[mt][nt][r];
      }
  // den partial: reduce over 16 kv lanes, combine kv-halves via LDS
  float dv[4];
#pragma unroll
  for (int r = 0; r < 4; ++r) {
    float v = den_acc[r];
    v += __shfl_xor(v, 1, 64);
    v += __shfl_xor(v, 2, 64);
    v += __shfl_xor(v, 4, 64);
    v += __shfl_xor(v, 8, 64);
    dv[r] = v;
  }
  if (l16 == 0) {
#pragma unroll
    for (int r = 0; r < 4; ++r)
      den_sh[kvh][hh * 16 + quad * 4 + r] = dv[r];
  }
  __syncthreads();
  if (t < 32) den_part[wg * 32 + t] = den_sh[0][t] + den_sh[1][t];
}

// --------------------------------------------- K4: reduce + divide + W_UV
__global__ __launch_bounds__(256) void k4_reduce_wuv(
    const float* __restrict__ num_part, const float* __restrict__ den_part,
    const float* __restrict__ W_UV, float* __restrict__ o_acc) {
  __shared__ float attn[32][33];
  __shared__ float den[32];
  const int t = threadIdx.x;
  const int lc = blockIdx.x, h = blockIdx.y;
  const int c0 = lc * 32;
  if (t < 32) {
    float s = 0.f;
    for (int p = 0; p < 16; ++p) s += den_part[(t * 16 + p) * 32 + h];
    den[t] = s;
  }
  __syncthreads();
  {
    const int l = t & 31, bg = t >> 5;
    for (int bb = 0; bb < 4; ++bb) {
      int b = bg * 4 + bb;
      float s = 0.f;
#pragma unroll
      for (int p = 0; p < 16; ++p)
        s += num_part[((size_t)(b * 16 + p) * 32 + h) * 512 + c0 + l];
      attn[b][l] = s / den[b];
    }
  }
  __syncthreads();
  const int v = t & 127, rg = t >> 7;
  float acc[16];
#pragma unroll
  for (int r = 0; r < 16; ++r) acc[r] = 0.f;
  for (int l = 0; l < 32; ++l) {
    float w = W_UV[(h * 512 + c0 + l) * 128 + v];
#pragma unroll
    for (int r = 0; r < 16; ++r) acc[r] += attn[rg * 16 + r][l] * w;
  }
  for (int r = 0; r < 16; ++r)
    atomicAdd(&o_acc[(size_t)(rg * 16 + r) * 4096 + h * 128 + v], acc[r]);
}

// -------------------------------------------------------- K5: o @ W_O
// grid (8 k-splits, 40 n-tiles of 128), bf16 MFMA, atomicAdd into zeroed out.
__global__ __launch_bounds__(256) void k5_wo(
    const float* __restrict__ o_acc, const float* __restrict__ W_O,
    float* __restrict__ out) {
  __shared__ uint32_t Bt[32 * 130];  // k-pair-zip of a 64k x 128n W_O chunk
  const int t = threadIdx.x;
  const int ksplit = blockIdx.x, ntile = blockIdx.y;
  const int n0 = ntile * 128, kbase = ksplit * 512;
  const int wave = t >> 6, lane = t & 63, quad = lane >> 4, l16 = lane & 15;
  const f32x4 fzero = {0.f, 0.f, 0.f, 0.f};
  f32x4 acc[2][2];
#pragma unroll
  for (int mt = 0; mt < 2; ++mt)
#pragma unroll
    for (int nt = 0; nt < 2; ++nt) acc[mt][nt] = fzero;
  for (int kc = 0; kc < 8; ++kc) {
    const int k0 = kbase + kc * 64;
    __syncthreads();
    for (int idx = t; idx < 4096; idx += 256) {
      int k2 = idx >> 7, col = idx & 127;
      float a = W_O[(size_t)(k0 + 2 * k2) * 5120 + n0 + col];
      float b = W_O[(size_t)(k0 + 2 * k2 + 1) * 5120 + n0 + col];
      Bt[k2 * 130 + col] = pack2bf(a, b);
    }
    __syncthreads();
#pragma unroll
    for (int ks2 = 0; ks2 < 2; ++ks2) {
      uint32_t af[2][4];
#pragma unroll
      for (int mt = 0; mt < 2; ++mt) {
        const float* orow =
            o_acc + (size_t)(mt * 16 + l16) * 4096 + k0 + ks2 * 32 + quad * 8;
#pragma unroll
        for (int i = 0; i < 4; ++i)
          af[mt][i] = pack2bf(orow[2 * i], orow[2 * i + 1]);
      }
#pragma unroll
      for (int nt = 0; nt < 2; ++nt) {
        uint32_t br[4];
#pragma unroll
        for (int i = 0; i < 4; ++i)
          br[i] = Bt[(ks2 * 16 + quad * 4 + i) * 130 + wave * 32 + nt * 16 + l16];
        short8 bf = frag_from(br);
        acc[0][nt] = __builtin_amdgcn_mfma_f32_16x16x32_bf16(
            frag_from(af[0]), bf, acc[0][nt], 0, 0, 0);
        acc[1][nt] = __builtin_amdgcn_mfma_f32_16x16x32_bf16(
            frag_from(af[1]), bf, acc[1][nt], 0, 0, 0);
      }
    }
  }
#pragma unroll
  for (int mt = 0; mt < 2; ++mt)
#pragma unroll
    for (int nt = 0; nt < 2; ++nt)
#pragma unroll
      for (int r = 0; r < 4; ++r) {
        int b = mt * 16 + quad * 4 + r;
        int c = n0 + wave * 32 + nt * 16 + l16;
        atomicAdd(&out[(size_t)b * 5120 + c], acc[mt][nt][r]);
      }
}

extern "C" void kernel_launch(void* const* d_in, const int* in_sizes, int n_in,
                              void* d_out, int out_size, void* d_ws,
                              size_t ws_size, hipStream_t stream) {
  (void)in_sizes; (void)n_in; (void)ws_size;
  const float* hidden = (const float*)d_in[0];
  const float* k_c    = (const float*)d_in[1];
  const float* k_pe   = (const float*)d_in[2];
  float* cache_k      = (float*)d_in[3];
  float* cache_v      = (float*)d_in[4];
  const float* W_Q    = (const float*)d_in[5];
  const float* W_UK   = (const float*)d_in[6];
  const float* W_QR   = (const float*)d_in[7];
  const float* W_UV   = (const float*)d_in[8];
  const float* W_O    = (const float*)d_in[9];
  const int* ipos     = (const int*)d_in[10];
  const int* blist    = (const int*)d_in[11];
  const int* bgroups  = (const int*)d_in[12];
  const float* bbias  = (const float*)d_in[13];
  const int* bindices = (const int*)d_in[14];
  const int* boffsets = (const int*)d_in[15];

  char* ws = (char*)d_ws;
  float*    q_nope0  = (float*)(ws);                 //   524288 B
  float*    q_pe0    = (float*)(ws + 524288);        //   262144 B
  float*    o_acc    = (float*)(ws + 786432);        //   524288 B
  uint16_t* q_bf     = (uint16_t*)(ws + 1310720);    //  1179648 B
  float*    den_part = (float*)(ws + 2490368);       //    65536 B
  float*    num_part = (float*)(ws + 2555904);       // 33554432 B  (36.1 MB total)
  float*    out      = (float*)d_out;

  hipMemsetAsync(ws, 0, 1310720, stream);                       // atomic targets
  hipMemsetAsync(d_out, 0, (size_t)out_size * sizeof(float), stream);

  k1_qproj<<<dim3(96, 2), 256, 0, stream>>>(hidden, W_Q, W_QR, q_nope0, q_pe0);
  k2_qlora<<<dim3(4, 32), 256, 0, stream>>>(q_nope0, W_UK, q_bf);
  k2b_rope_scatter<<<32, 256, 0, stream>>>(q_pe0, k_pe, k_c, ipos, bindices,
                                           boffsets, cache_k, cache_v, q_bf);
  k3_attn<<<dim3(16, 32), 256, 0, stream>>>(q_bf, cache_k, cache_v, blist,
                                            bgroups, bbias, num_part, den_part);
  k4_reduce_wuv<<<dim3(16, 32), 256, 0, stream>>>(num_part, den_part, W_UV, o_acc);
  k5_wo<<<dim3(8, 40), 256, 0, stream>>>(o_acc, W_O, out);
}

// Round 2
// 702.716 us; speedup vs baseline: 1.4845x; 1.4845x over previous
//
#include <hip/hip_runtime.h>
#include <stdint.h>

// MLA decode: B=32, H=32, KV_LORA=512, ROPE=64, NOPE=128, VH=128, QL=1536,
// HID=5120, BLK=128, 32 blocks/seq, NB=1024. fp32 in/out, bf16 MFMA internals.

typedef __attribute__((ext_vector_type(8))) short short8;
typedef __attribute__((ext_vector_type(4))) float f32x4;

__device__ inline uint32_t f2bf(float f) {
  uint32_t u = __float_as_uint(f);
  return (u + 0x7fffu + ((u >> 16) & 1u)) >> 16;   // RNE
}
__device__ inline uint32_t pack2bf(float lo, float hi) {
  return f2bf(lo) | (f2bf(hi) << 16);
}
union FragU { uint32_t u[4]; short8 s; };
__device__ inline short8 frag_from(const uint32_t r[4]) {
  FragU v; v.u[0] = r[0]; v.u[1] = r[1]; v.u[2] = r[2]; v.u[3] = r[3];
  return v.s;
}

// ---------------------------------------------------------------- K1: q proj
// out[b][c] = sum_k hidden[b][k] * W[k][c], W = [W_Q (4096 cols) | W_QR (2048)]
// grid (48 col-tiles of 128, 12 k-splits of 128) = 576 blocks (2.25/CU).
// float4 W loads, acc[4 rows][4 cols]/thread, atomicAdd into zeroed outputs.
__global__ __launch_bounds__(256) void k1_qproj(
    const float* __restrict__ hidden, const float* __restrict__ W_Q,
    const float* __restrict__ W_QR, float* __restrict__ q_nope0,
    float* __restrict__ q_pe0) {
  __shared__ float hl[32][129];
  const int t = threadIdx.x;
  const int ctile = blockIdx.x * 128;
  const int k0 = blockIdx.y * 128;
  const bool isQ = (ctile < 4096);
  const float* W = isQ ? W_Q : W_QR;
  const int wstride = isQ ? 4096 : 2048;
  const int c = (isQ ? ctile : ctile - 4096) + (t & 31) * 4;
  const int rg = t >> 5;  // 8 groups x 4 batch rows
  for (int idx = t; idx < 4096; idx += 256) {
    int b = idx >> 7, kk = idx & 127;
    hl[b][kk] = hidden[b * 1536 + k0 + kk];
  }
  __syncthreads();
  float acc[4][4];
#pragma unroll
  for (int r = 0; r < 4; ++r)
#pragma unroll
    for (int j = 0; j < 4; ++j) acc[r][j] = 0.f;
  const float* wp = W + (size_t)k0 * wstride + c;
#pragma unroll 4
  for (int kk = 0; kk < 128; ++kk) {
    float4 w = *(const float4*)wp;
    wp += wstride;
#pragma unroll
    for (int r = 0; r < 4; ++r) {
      float hv = hl[rg * 4 + r][kk];
      acc[r][0] += hv * w.x;
      acc[r][1] += hv * w.y;
      acc[r][2] += hv * w.z;
      acc[r][3] += hv * w.w;
    }
  }
  float* dst = isQ ? q_nope0 : q_pe0;
#pragma unroll
  for (int r = 0; r < 4; ++r)
#pragma unroll
    for (int j = 0; j < 4; ++j)
      atomicAdd(&dst[(rg * 4 + r) * wstride + c + j], acc[r][j]);
}

// --------------------------------------------------------------- K2: q_lora
// q_acc[b][h][c] += sum_d q_nope0[b][h*128+d] * W_UK[h][d][c]  (fp32 atomics)
// grid (4 c-tiles of 128, 32 heads, 2 d-splits of 64) = 256 blocks.
__global__ __launch_bounds__(256) void k2_qlora(
    const float* __restrict__ q_nope0, const float* __restrict__ W_UK,
    float* __restrict__ q_acc) {
  __shared__ float qn[32][65];
  const int t = threadIdx.x;
  const int h = blockIdx.y;
  const int c0 = blockIdx.x * 128;
  const int d0 = blockIdx.z * 64;
  for (int idx = t; idx < 2048; idx += 256) {
    int b = idx >> 6, dd = idx & 63;
    qn[b][dd] = q_nope0[b * 4096 + h * 128 + d0 + dd];
  }
  __syncthreads();
  const int c = c0 + (t & 31) * 4;
  const int rg = t >> 5;  // 8 groups x 4 batch rows
  float acc[4][4];
#pragma unroll
  for (int r = 0; r < 4; ++r)
#pragma unroll
    for (int j = 0; j < 4; ++j) acc[r][j] = 0.f;
  const float* wp = W_UK + (size_t)(h * 128 + d0) * 512 + c;
#pragma unroll 4
  for (int dd = 0; dd < 64; ++dd) {
    float4 w = *(const float4*)wp;
    wp += 512;
#pragma unroll
    for (int r = 0; r < 4; ++r) {
      float qv = qn[rg * 4 + r][dd];
      acc[r][0] += qv * w.x;
      acc[r][1] += qv * w.y;
      acc[r][2] += qv * w.z;
      acc[r][3] += qv * w.w;
    }
  }
#pragma unroll
  for (int r = 0; r < 4; ++r)
#pragma unroll
    for (int j = 0; j < 4; ++j)
      atomicAdd(&q_acc[(size_t)((rg * 4 + r) * 32 + h) * 512 + c + j],
                acc[r][j]);
}

// ------------------------- K2b: RoPE + cache scatter + q_acc->bf16 convert
__global__ __launch_bounds__(256) void k2b_rope_scatter(
    const float* __restrict__ q_pe0, const float* __restrict__ k_pe,
    const float* __restrict__ k_c_normed, const int* __restrict__ ipos,
    const int* __restrict__ bindices, const int* __restrict__ boffsets,
    const float* __restrict__ q_acc, float* __restrict__ cache_k,
    float* __restrict__ cache_v, uint16_t* __restrict__ q_bf) {
  const int b = blockIdx.x;
  const int t = threadIdx.x;
  const float pos = (float)ipos[b];
  const float scale = 0.07216878364870323f;  // 1/sqrt(192)
  const float lnk = 0.28782313662425575f;    // ln(10000)/32
  // nope part: scale + convert
  for (int idx = t; idx < 16384; idx += 256) {
    int h = idx >> 9, c = idx & 511;
    q_bf[((size_t)b * 32 + h) * 576 + c] =
        (uint16_t)f2bf(q_acc[((size_t)b * 32 + h) * 512 + c] * scale);
  }
  // rope part of q
  for (int idx = t; idx < 1024; idx += 256) {
    int h = idx >> 5, i = idx & 31;
    float ang = pos * __expf(-(float)i * lnk);
    float s, c;
    sincosf(ang, &s, &c);
    float x1 = q_pe0[b * 2048 + h * 64 + i];
    float x2 = q_pe0[b * 2048 + h * 64 + 32 + i];
    int base = (b * 32 + h) * 576 + 512;
    q_bf[base + i]      = (uint16_t)f2bf((x1 * c - x2 * s) * scale);
    q_bf[base + 32 + i] = (uint16_t)f2bf((x2 * c + x1 * s) * scale);
  }
  const int row = bindices[b] * 128 + boffsets[b];
  if (t < 32) {
    int i = t;
    float ang = pos * __expf(-(float)i * lnk);
    float s, c;
    sincosf(ang, &s, &c);
    float x1 = k_pe[b * 64 + i], x2 = k_pe[b * 64 + 32 + i];
    cache_k[row * 64 + i]      = x1 * c - x2 * s;
    cache_k[row * 64 + 32 + i] = x2 * c + x1 * s;
  }
  for (int j = t; j < 512; j += 256)
    cache_v[row * 512 + j] = k_c_normed[b * 512 + j];
}

// ------------------------------------------------------------ K3: attention
// grid (16 parts, 32 seqs), 256 thr (4 waves), 2 blocks/WG, 32-kv sub-tiles.
// LDS tile Tl: d-pair-zip  Tl[d2*33+kv] = {T[kv][2d2], T[kv][2d2+1]} (bf16 pair)
// Logits B-frag = direct b32 reads; PV B-frag = 8x b32 + 16-bit extract.
__global__ __launch_bounds__(256, 2) void k3_attn(
    const uint16_t* __restrict__ q_bf, const float* __restrict__ cache_k,
    const float* __restrict__ cache_v, const int* __restrict__ block_list,
    const int* __restrict__ block_groups, const float* __restrict__ block_bias,
    float* __restrict__ num_part, float* __restrict__ den_part) {
  __shared__ uint32_t Tl[288 * 33];
  __shared__ uint32_t Pl[16 * 33];
  __shared__ float den_sh[2][32];

  const int t = threadIdx.x;
  const int part = blockIdx.x, bseq = blockIdx.y;
  const int wg = bseq * 16 + part;
  const int wave = t >> 6, lane = t & 63, quad = lane >> 4, l16 = lane & 15;
  const int hh = wave >> 1, kvh = wave & 1;
  const int n0 = bseq * 32 + part * 2;
  const int g = block_groups[n0];

  // Q fragments (this wave's 16-head half), 72 dwords in registers
  uint32_t qf[72];
  {
    const uint32_t* qrow =
        (const uint32_t*)(q_bf + (size_t)(g * 32 + hh * 16 + l16) * 576);
#pragma unroll
    for (int ks = 0; ks < 18; ++ks)
#pragma unroll
      for (int i = 0; i < 4; ++i)
        qf[ks * 4 + i] = qrow[ks * 16 + quad * 4 + i];
  }

  const f32x4 fzero = {0.f, 0.f, 0.f, 0.f};
  f32x4 acc[2][8];
#pragma unroll
  for (int mt = 0; mt < 2; ++mt)
#pragma unroll
    for (int nt = 0; nt < 8; ++nt) acc[mt][nt] = fzero;
  float den_acc[4] = {0.f, 0.f, 0.f, 0.f};

  for (int blk_i = 0; blk_i < 2; ++blk_i) {
    const int n = n0 + blk_i;
    const int phys = block_list[n];
    const float* vrow = cache_v + (size_t)phys * 128 * 512;
    const float* krow = cache_k + (size_t)phys * 128 * 64;
    for (int s = 0; s < 4; ++s) {
      const int s0 = s * 32;
      __syncthreads();  // previous PV readers done
      for (int idx = t; idx < 4608; idx += 256) {   // 32 kv x 144 float4
        int kv = idx / 144, f4 = idx - kv * 144;
        float4 v; int d0;
        if (f4 < 128) { v = *(const float4*)(vrow + (s0 + kv) * 512 + f4 * 4); d0 = f4 * 4; }
        else { v = *(const float4*)(krow + (s0 + kv) * 64 + (f4 - 128) * 4); d0 = 512 + (f4 - 128) * 4; }
        int d2 = d0 >> 1;
        Tl[(d2    ) * 33 + kv] = pack2bf(v.x, v.y);
        Tl[(d2 + 1) * 33 + kv] = pack2bf(v.z, v.w);
      }
      __syncthreads();
      // ---- logits: wave computes 16h x 16kv tile (hh, kvh), K = 576
      const int tkv = kvh * 16 + l16;
      f32x4 lg = fzero;
#pragma unroll
      for (int ks = 0; ks < 18; ++ks) {
        uint32_t br[4];
#pragma unroll
        for (int i = 0; i < 4; ++i)
          br[i] = Tl[(ks * 16 + quad * 4 + i) * 33 + tkv];
        lg = __builtin_amdgcn_mfma_f32_16x16x32_bf16(
            frag_from(&qf[ks * 4]), frag_from(br), lg, 0, 0, 0);
      }
      float bias = block_bias[n * 128 + s0 + tkv];
      uint32_t pb[4];
#pragma unroll
      for (int r = 0; r < 4; ++r) {
        float p = __expf(lg[r] + bias);   // no shift: |logit| <= ~9, safe
        pb[r] = f2bf(p);
        den_acc[r] += __uint_as_float(pb[r] << 16);
      }
#pragma unroll
      for (int r = 0; r < 4; ++r) {       // kv-pair-zip P into LDS
        uint32_t other = (uint32_t)__shfl_xor((int)pb[r], 1, 64);
        if ((l16 & 1) == 0) {
          int h = hh * 16 + quad * 4 + r;
          Pl[(tkv >> 1) * 33 + h] = pb[r] | (other << 16);
        }
      }
      __syncthreads();
      // ---- PV: wave handles l-slice [wave*128, wave*128+128)
      uint32_t af[2][4];
#pragma unroll
      for (int mt = 0; mt < 2; ++mt)
#pragma unroll
        for (int i = 0; i < 4; ++i)
          af[mt][i] = Pl[(quad * 4 + i) * 33 + mt * 16 + l16];
#pragma unroll
      for (int nt = 0; nt < 8; ++nt) {
        int l = wave * 128 + nt * 16 + l16;
        const uint32_t* base = &Tl[(l >> 1) * 33 + quad * 8];
        uint32_t dw[8];
#pragma unroll
        for (int j = 0; j < 8; ++j) dw[j] = base[j];
        uint32_t br[4];
        const bool odd = (l & 1);
#pragma unroll
        for (int i = 0; i < 4; ++i) {
          uint32_t a = dw[2 * i], bq = dw[2 * i + 1];
          uint32_t lo = odd ? (a >> 16) : (a & 0xffffu);
          uint32_t hi = odd ? (bq & 0xffff0000u) : (bq << 16);
          br[i] = lo | hi;
        }
        short8 bf = frag_from(br);
        acc[0][nt] = __builtin_amdgcn_mfma_f32_16x16x32_bf16(
            frag_from(af[0]), bf, acc[0][nt], 0, 0, 0);
        acc[1][nt] = __builtin_amdgcn_mfma_f32_16x16x32_bf16(
            frag_from(af[1]), bf, acc[1][nt], 0, 0, 0);
      }
    }
  }
  // write num partial (coalesced over l16)
#pragma unroll
  for (int mt = 0; mt < 2; ++mt)
#pragma unroll
    for (int nt = 0; nt < 8; ++nt)
#pragma unroll
      for (int r = 0; r < 4; ++r) {
        int h = mt * 16 + quad * 4 + r;
        int l = wave * 128 + nt * 16 + l16;
        num_part[((size_t)wg * 32 + h) * 512 + l] = acc[mt][nt][r];
      }
  // den partial: reduce over 16 kv lanes, combine kv-halves via LDS
  float dv[4];
#pragma unroll
  for (int r = 0; r < 4; ++r) {
    float v = den_acc[r];
    v += __shfl_xor(v, 1, 64);
    v += __shfl_xor(v, 2, 64);
    v += __shfl_xor(v, 4, 64);
    v += __shfl_xor(v, 8, 64);
    dv[r] = v;
  }
  if (l16 == 0) {
#pragma unroll
    for (int r = 0; r < 4; ++r)
      den_sh[kvh][hh * 16 + quad * 4 + r] = dv[r];
  }
  __syncthreads();
  if (t < 32) den_part[wg * 32 + t] = den_sh[0][t] + den_sh[1][t];
}

// --------------------------------------------- K4: reduce + divide + W_UV
__global__ __launch_bounds__(256) void k4_reduce_wuv(
    const float* __restrict__ num_part, const float* __restrict__ den_part,
    const float* __restrict__ W_UV, float* __restrict__ o_acc) {
  __shared__ float attn[32][33];
  __shared__ float den[32];
  const int t = threadIdx.x;
  const int lc = blockIdx.x, h = blockIdx.y;
  const int c0 = lc * 32;
  if (t < 32) {
    float s = 0.f;
    for (int p = 0; p < 16; ++p) s += den_part[(t * 16 + p) * 32 + h];
    den[t] = s;
  }
  __syncthreads();
  {
    const int l = t & 31, bg = t >> 5;
    for (int bb = 0; bb < 4; ++bb) {
      int b = bg * 4 + bb;
      float s = 0.f;
#pragma unroll
      for (int p = 0; p < 16; ++p)
        s += num_part[((size_t)(b * 16 + p) * 32 + h) * 512 + c0 + l];
      attn[b][l] = s / den[b];
    }
  }
  __syncthreads();
  const int v = t & 127, rg = t >> 7;
  float acc[16];
#pragma unroll
  for (int r = 0; r < 16; ++r) acc[r] = 0.f;
  for (int l = 0; l < 32; ++l) {
    float w = W_UV[(h * 512 + c0 + l) * 128 + v];
#pragma unroll
    for (int r = 0; r < 16; ++r) acc[r] += attn[rg * 16 + r][l] * w;
  }
  for (int r = 0; r < 16; ++r)
    atomicAdd(&o_acc[(size_t)(rg * 16 + r) * 4096 + h * 128 + v], acc[r]);
}

// -------------------------------------------------------- K5: o @ W_O
// grid (16 k-splits of 256, 40 n-tiles of 128), bf16 MFMA, float4 staging,
// atomicAdd into zeroed out.
__global__ __launch_bounds__(256) void k5_wo(
    const float* __restrict__ o_acc, const float* __restrict__ W_O,
    float* __restrict__ out) {
  __shared__ uint32_t Bt[32 * 130];  // k-pair-zip of a 64k x 128n W_O chunk
  const int t = threadIdx.x;
  const int ksplit = blockIdx.x, ntile = blockIdx.y;
  const int n0 = ntile * 128, kbase = ksplit * 256;
  const int wave = t >> 6, lane = t & 63, quad = lane >> 4, l16 = lane & 15;
  const f32x4 fzero = {0.f, 0.f, 0.f, 0.f};
  f32x4 acc[2][2];
#pragma unroll
  for (int mt = 0; mt < 2; ++mt)
#pragma unroll
    for (int nt = 0; nt < 2; ++nt) acc[mt][nt] = fzero;
  for (int kc = 0; kc < 4; ++kc) {
    const int k0 = kbase + kc * 64;
    __syncthreads();
    for (int idx = t; idx < 1024; idx += 256) {  // k2 in [0,32) x c4 in [0,32)
      int k2 = idx >> 5, c4 = idx & 31;
      const float* p0 = &W_O[(size_t)(k0 + 2 * k2) * 5120 + n0 + c4 * 4];
      float4 a = *(const float4*)p0;
      float4 b = *(const float4*)(p0 + 5120);
      uint32_t* bp = &Bt[k2 * 130 + c4 * 4];
      bp[0] = pack2bf(a.x, b.x);
      bp[1] = pack2bf(a.y, b.y);
      bp[2] = pack2bf(a.z, b.z);
      bp[3] = pack2bf(a.w, b.w);
    }
    __syncthreads();
#pragma unroll
    for (int ks2 = 0; ks2 < 2; ++ks2) {
      uint32_t af[2][4];
#pragma unroll
      for (int mt = 0; mt < 2; ++mt) {
        const float* orow =
            o_acc + (size_t)(mt * 16 + l16) * 4096 + k0 + ks2 * 32 + quad * 8;
        float4 x = *(const float4*)orow;
        float4 y = *(const float4*)(orow + 4);
        af[mt][0] = pack2bf(x.x, x.y);
        af[mt][1] = pack2bf(x.z, x.w);
        af[mt][2] = pack2bf(y.x, y.y);
        af[mt][3] = pack2bf(y.z, y.w);
      }
#pragma unroll
      for (int nt = 0; nt < 2; ++nt) {
        uint32_t br[4];
#pragma unroll
        for (int i = 0; i < 4; ++i)
          br[i] = Bt[(ks2 * 16 + quad * 4 + i) * 130 + wave * 32 + nt * 16 + l16];
        short8 bf = frag_from(br);
        acc[0][nt] = __builtin_amdgcn_mfma_f32_16x16x32_bf16(
            frag_from(af[0]), bf, acc[0][nt], 0, 0, 0);
        acc[1][nt] = __builtin_amdgcn_mfma_f32_16x16x32_bf16(
            frag_from(af[1]), bf, acc[1][nt], 0, 0, 0);
      }
    }
  }
#pragma unroll
  for (int mt = 0; mt < 2; ++mt)
#pragma unroll
    for (int nt = 0; nt < 2; ++nt)
#pragma unroll
      for (int r = 0; r < 4; ++r) {
        int b = mt * 16 + quad * 4 + r;
        int c = n0 + wave * 32 + nt * 16 + l16;
        atomicAdd(&out[(size_t)b * 5120 + c], acc[mt][nt][r]);
      }
}

extern "C" void kernel_launch(void* const* d_in, const int* in_sizes, int n_in,
                              void* d_out, int out_size, void* d_ws,
                              size_t ws_size, hipStream_t stream) {
  (void)in_sizes; (void)n_in; (void)ws_size;
  const float* hidden = (const float*)d_in[0];
  const float* k_c    = (const float*)d_in[1];
  const float* k_pe   = (const float*)d_in[2];
  float* cache_k      = (float*)d_in[3];
  float* cache_v      = (float*)d_in[4];
  const float* W_Q    = (const float*)d_in[5];
  const float* W_UK   = (const float*)d_in[6];
  const float* W_QR   = (const float*)d_in[7];
  const float* W_UV   = (const float*)d_in[8];
  const float* W_O    = (const float*)d_in[9];
  const int* ipos     = (const int*)d_in[10];
  const int* blist    = (const int*)d_in[11];
  const int* bgroups  = (const int*)d_in[12];
  const float* bbias  = (const float*)d_in[13];
  const int* bindices = (const int*)d_in[14];
  const int* boffsets = (const int*)d_in[15];

  char* ws = (char*)d_ws;
  float*    q_nope0  = (float*)(ws);                 //   524288 B
  float*    q_pe0    = (float*)(ws + 524288);        //   262144 B
  float*    o_acc    = (float*)(ws + 786432);        //   524288 B
  uint16_t* q_bf     = (uint16_t*)(ws + 1310720);    //  1179648 B
  float*    den_part = (float*)(ws + 2490368);       //    65536 B
  float*    num_part = (float*)(ws + 2555904);       // 33554432 B  (36.1 MB total)
  // q_acc (2 MB, fp32 32x32x512) aliases num_part: dead before k3 writes it.
  float*    q_acc    = num_part;
  float*    out      = (float*)d_out;

  hipMemsetAsync(ws, 0, 1310720, stream);            // q_nope0, q_pe0, o_acc
  hipMemsetAsync((void*)q_acc, 0, 2097152, stream);  // q_acc (atomic target)
  hipMemsetAsync(d_out, 0, (size_t)out_size * sizeof(float), stream);

  k1_qproj<<<dim3(48, 12), 256, 0, stream>>>(hidden, W_Q, W_QR, q_nope0, q_pe0);
  k2_qlora<<<dim3(4, 32, 2), 256, 0, stream>>>(q_nope0, W_UK, q_acc);
  k2b_rope_scatter<<<32, 256, 0, stream>>>(q_pe0, k_pe, k_c, ipos, bindices,
                                           boffsets, q_acc, cache_k, cache_v,
                                           q_bf);
  k3_attn<<<dim3(16, 32), 256, 0, stream>>>(q_bf, cache_k, cache_v, blist,
                                            bgroups, bbias, num_part, den_part);
  k4_reduce_wuv<<<dim3(16, 32), 256, 0, stream>>>(num_part, den_part, W_UV, o_acc);
  k5_wo<<<dim3(16, 40), 256, 0, stream>>>(o_acc, W_O, out);
}

// Round 3
// 702.377 us; speedup vs baseline: 1.4852x; 1.0005x over previous
//
#include <hip/hip_runtime.h>
#include <hip/hip_bf16.h>
#include <stdint.h>

// MLA decode: B=32, H=32, KV_LORA=512, ROPE=64, NOPE=128, VH=128, QL=1536,
// HID=5120, BLK=128, 32 blocks/seq, NB=1024. fp32 in/out, bf16 MFMA internals.

typedef __attribute__((ext_vector_type(8))) short short8;
typedef __attribute__((ext_vector_type(4))) float f32x4;

__device__ inline uint32_t f2bf(float f) {
  uint32_t u = __float_as_uint(f);
  return (u + 0x7fffu + ((u >> 16) & 1u)) >> 16;   // RNE
}
// packed f32x2 -> bf16x2 via v_cvt_pk_bf16_f32 (gfx950)
union Bf2U { __hip_bfloat162 h; uint32_t u; };
__device__ inline uint32_t pack2bf(float lo, float hi) {
  Bf2U v; v.h = __float22bfloat162_rn(float2{lo, hi});
  return v.u;
}
union FragU { uint32_t u[4]; short8 s; };
__device__ inline short8 frag_from(const uint32_t r[4]) {
  FragU v; v.u[0] = r[0]; v.u[1] = r[1]; v.u[2] = r[2]; v.u[3] = r[3];
  return v.s;
}

// ---------------------------------------------------------------- K1: q proj
// out[b][c] = sum_k hidden[b][k] * W[k][c], W = [W_Q (4096 cols) | W_QR (2048)]
// grid (48 col-tiles of 128, 12 k-splits of 128) = 576 blocks (2.25/CU).
__global__ __launch_bounds__(256) void k1_qproj(
    const float* __restrict__ hidden, const float* __restrict__ W_Q,
    const float* __restrict__ W_QR, float* __restrict__ q_nope0,
    float* __restrict__ q_pe0) {
  __shared__ float hl[32][129];
  const int t = threadIdx.x;
  const int ctile = blockIdx.x * 128;
  const int k0 = blockIdx.y * 128;
  const bool isQ = (ctile < 4096);
  const float* W = isQ ? W_Q : W_QR;
  const int wstride = isQ ? 4096 : 2048;
  const int c = (isQ ? ctile : ctile - 4096) + (t & 31) * 4;
  const int rg = t >> 5;  // 8 groups x 4 batch rows
  for (int idx = t; idx < 4096; idx += 256) {
    int b = idx >> 7, kk = idx & 127;
    hl[b][kk] = hidden[b * 1536 + k0 + kk];
  }
  __syncthreads();
  float acc[4][4];
#pragma unroll
  for (int r = 0; r < 4; ++r)
#pragma unroll
    for (int j = 0; j < 4; ++j) acc[r][j] = 0.f;
  const float* wp = W + (size_t)k0 * wstride + c;
#pragma unroll 4
  for (int kk = 0; kk < 128; ++kk) {
    float4 w = *(const float4*)wp;
    wp += wstride;
#pragma unroll
    for (int r = 0; r < 4; ++r) {
      float hv = hl[rg * 4 + r][kk];
      acc[r][0] += hv * w.x;
      acc[r][1] += hv * w.y;
      acc[r][2] += hv * w.z;
      acc[r][3] += hv * w.w;
    }
  }
  float* dst = isQ ? q_nope0 : q_pe0;
#pragma unroll
  for (int r = 0; r < 4; ++r)
#pragma unroll
    for (int j = 0; j < 4; ++j)
      atomicAdd(&dst[(rg * 4 + r) * wstride + c + j], acc[r][j]);
}

// --------------------------------------------------------------- K2: q_lora
// q_acc[b][h][c] += sum_d q_nope0[b][h*128+d] * W_UK[h][d][c]  (fp32 atomics)
// grid (4 c-tiles of 128, 32 heads, 4 d-splits of 32) = 512 blocks (2/CU).
__global__ __launch_bounds__(256) void k2_qlora(
    const float* __restrict__ q_nope0, const float* __restrict__ W_UK,
    float* __restrict__ q_acc) {
  __shared__ float qn[32][33];
  const int t = threadIdx.x;
  const int h = blockIdx.y;
  const int c0 = blockIdx.x * 128;
  const int d0 = blockIdx.z * 32;
  for (int idx = t; idx < 1024; idx += 256) {
    int b = idx >> 5, dd = idx & 31;
    qn[b][dd] = q_nope0[b * 4096 + h * 128 + d0 + dd];
  }
  __syncthreads();
  const int c = c0 + (t & 31) * 4;
  const int rg = t >> 5;  // 8 groups x 4 batch rows
  float acc[4][4];
#pragma unroll
  for (int r = 0; r < 4; ++r)
#pragma unroll
    for (int j = 0; j < 4; ++j) acc[r][j] = 0.f;
  const float* wp = W_UK + (size_t)(h * 128 + d0) * 512 + c;
#pragma unroll 4
  for (int dd = 0; dd < 32; ++dd) {
    float4 w = *(const float4*)wp;
    wp += 512;
#pragma unroll
    for (int r = 0; r < 4; ++r) {
      float qv = qn[rg * 4 + r][dd];
      acc[r][0] += qv * w.x;
      acc[r][1] += qv * w.y;
      acc[r][2] += qv * w.z;
      acc[r][3] += qv * w.w;
    }
  }
#pragma unroll
  for (int r = 0; r < 4; ++r)
#pragma unroll
    for (int j = 0; j < 4; ++j)
      atomicAdd(&q_acc[(size_t)((rg * 4 + r) * 32 + h) * 512 + c + j],
                acc[r][j]);
}

// ------------------------- K2b: RoPE + cache scatter + q_acc->bf16 convert
// grid (32 seqs, 8 head-slices of 4) = 256 blocks.
__global__ __launch_bounds__(256) void k2b_rope_scatter(
    const float* __restrict__ q_pe0, const float* __restrict__ k_pe,
    const float* __restrict__ k_c_normed, const int* __restrict__ ipos,
    const int* __restrict__ bindices, const int* __restrict__ boffsets,
    const float* __restrict__ q_acc, float* __restrict__ cache_k,
    float* __restrict__ cache_v, uint16_t* __restrict__ q_bf) {
  const int b = blockIdx.x;
  const int hs = blockIdx.y * 4;   // 4 heads per block
  const int t = threadIdx.x;
  const float pos = (float)ipos[b];
  const float scale = 0.07216878364870323f;  // 1/sqrt(192)
  const float lnk = 0.28782313662425575f;    // ln(10000)/32
  // nope part: scale + convert (4 heads x 512 c)
  for (int idx = t; idx < 2048; idx += 256) {
    int h = hs + (idx >> 9), c = idx & 511;
    q_bf[((size_t)b * 32 + h) * 576 + c] =
        (uint16_t)f2bf(q_acc[((size_t)b * 32 + h) * 512 + c] * scale);
  }
  // rope part of q (4 heads x 32 pairs)
  if (t < 128) {
    int h = hs + (t >> 5), i = t & 31;
    float ang = pos * __expf(-(float)i * lnk);
    float s, c;
    sincosf(ang, &s, &c);
    float x1 = q_pe0[b * 2048 + h * 64 + i];
    float x2 = q_pe0[b * 2048 + h * 64 + 32 + i];
    int base = (b * 32 + h) * 576 + 512;
    q_bf[base + i]      = (uint16_t)f2bf((x1 * c - x2 * s) * scale);
    q_bf[base + 32 + i] = (uint16_t)f2bf((x2 * c + x1 * s) * scale);
  }
  if (blockIdx.y == 0) {
    const int row = bindices[b] * 128 + boffsets[b];
    if (t < 32) {
      int i = t;
      float ang = pos * __expf(-(float)i * lnk);
      float s, c;
      sincosf(ang, &s, &c);
      float x1 = k_pe[b * 64 + i], x2 = k_pe[b * 64 + 32 + i];
      cache_k[row * 64 + i]      = x1 * c - x2 * s;
      cache_k[row * 64 + 32 + i] = x2 * c + x1 * s;
    }
    for (int j = t; j < 512; j += 256)
      cache_v[row * 512 + j] = k_c_normed[b * 512 + j];
  }
}

// ------------------------------------------------------------ K3: attention
// grid (16 parts, 32 seqs), 256 thr (4 waves), 2 blocks/WG, 32-kv sub-tiles.
// LDS tile Tl: d-pair-zip  Tl[d2*33+kv] = {T[kv][2d2], T[kv][2d2+1]} (bf16 pair)
// Logits B-frag = direct b32 reads; PV B-frag = 8x b32 + 16-bit extract.
__global__ __launch_bounds__(256, 2) void k3_attn(
    const uint16_t* __restrict__ q_bf, const float* __restrict__ cache_k,
    const float* __restrict__ cache_v, const int* __restrict__ block_list,
    const int* __restrict__ block_groups, const float* __restrict__ block_bias,
    float* __restrict__ num_part, float* __restrict__ den_part) {
  __shared__ uint32_t Tl[288 * 33];
  __shared__ uint32_t Pl[16 * 33];
  __shared__ float den_sh[2][32];

  const int t = threadIdx.x;
  const int part = blockIdx.x, bseq = blockIdx.y;
  const int wg = bseq * 16 + part;
  const int wave = t >> 6, lane = t & 63, quad = lane >> 4, l16 = lane & 15;
  const int hh = wave >> 1, kvh = wave & 1;
  const int n0 = bseq * 32 + part * 2;
  const int g = block_groups[n0];

  // Q fragments (this wave's 16-head half), 72 dwords in registers
  uint32_t qf[72];
  {
    const uint32_t* qrow =
        (const uint32_t*)(q_bf + (size_t)(g * 32 + hh * 16 + l16) * 576);
#pragma unroll
    for (int ks = 0; ks < 18; ++ks)
#pragma unroll
      for (int i = 0; i < 4; ++i)
        qf[ks * 4 + i] = qrow[ks * 16 + quad * 4 + i];
  }

  const f32x4 fzero = {0.f, 0.f, 0.f, 0.f};
  f32x4 acc[2][8];
#pragma unroll
  for (int mt = 0; mt < 2; ++mt)
#pragma unroll
    for (int nt = 0; nt < 8; ++nt) acc[mt][nt] = fzero;
  float den_acc[4] = {0.f, 0.f, 0.f, 0.f};

  for (int blk_i = 0; blk_i < 2; ++blk_i) {
    const int n = n0 + blk_i;
    const int phys = block_list[n];
    const float* vrow = cache_v + (size_t)phys * 128 * 512;
    const float* krow = cache_k + (size_t)phys * 128 * 64;
    for (int s = 0; s < 4; ++s) {
      const int s0 = s * 32;
      __syncthreads();  // previous PV readers done
      for (int idx = t; idx < 4608; idx += 256) {   // 32 kv x 144 float4
        int kv = idx / 144, f4 = idx - kv * 144;
        float4 v; int d0;
        if (f4 < 128) { v = *(const float4*)(vrow + (s0 + kv) * 512 + f4 * 4); d0 = f4 * 4; }
        else { v = *(const float4*)(krow + (s0 + kv) * 64 + (f4 - 128) * 4); d0 = 512 + (f4 - 128) * 4; }
        int d2 = d0 >> 1;
        Tl[(d2    ) * 33 + kv] = pack2bf(v.x, v.y);
        Tl[(d2 + 1) * 33 + kv] = pack2bf(v.z, v.w);
      }
      __syncthreads();
      // ---- logits: wave computes 16h x 16kv tile (hh, kvh), K = 576
      const int tkv = kvh * 16 + l16;
      f32x4 lg = fzero;
#pragma unroll
      for (int ks = 0; ks < 18; ++ks) {
        uint32_t br[4];
#pragma unroll
        for (int i = 0; i < 4; ++i)
          br[i] = Tl[(ks * 16 + quad * 4 + i) * 33 + tkv];
        lg = __builtin_amdgcn_mfma_f32_16x16x32_bf16(
            frag_from(&qf[ks * 4]), frag_from(br), lg, 0, 0, 0);
      }
      float bias = block_bias[n * 128 + s0 + tkv];
      uint32_t pb[4];
#pragma unroll
      for (int r = 0; r < 4; ++r) {
        float p = __expf(lg[r] + bias);   // no shift: |logit| <= ~9, safe
        pb[r] = f2bf(p);
        den_acc[r] += __uint_as_float(pb[r] << 16);
      }
#pragma unroll
      for (int r = 0; r < 4; ++r) {       // kv-pair-zip P into LDS
        uint32_t other = (uint32_t)__shfl_xor((int)pb[r], 1, 64);
        if ((l16 & 1) == 0) {
          int h = hh * 16 + quad * 4 + r;
          Pl[(tkv >> 1) * 33 + h] = pb[r] | (other << 16);
        }
      }
      __syncthreads();
      // ---- PV: wave handles l-slice [wave*128, wave*128+128)
      uint32_t af[2][4];
#pragma unroll
      for (int mt = 0; mt < 2; ++mt)
#pragma unroll
        for (int i = 0; i < 4; ++i)
          af[mt][i] = Pl[(quad * 4 + i) * 33 + mt * 16 + l16];
#pragma unroll
      for (int nt = 0; nt < 8; ++nt) {
        int l = wave * 128 + nt * 16 + l16;
        const uint32_t* base = &Tl[(l >> 1) * 33 + quad * 8];
        uint32_t dw[8];
#pragma unroll
        for (int j = 0; j < 8; ++j) dw[j] = base[j];
        uint32_t br[4];
        const bool odd = (l & 1);
#pragma unroll
        for (int i = 0; i < 4; ++i) {
          uint32_t a = dw[2 * i], bq = dw[2 * i + 1];
          uint32_t lo = odd ? (a >> 16) : (a & 0xffffu);
          uint32_t hi = odd ? (bq & 0xffff0000u) : (bq << 16);
          br[i] = lo | hi;
        }
        short8 bf = frag_from(br);
        acc[0][nt] = __builtin_amdgcn_mfma_f32_16x16x32_bf16(
            frag_from(af[0]), bf, acc[0][nt], 0, 0, 0);
        acc[1][nt] = __builtin_amdgcn_mfma_f32_16x16x32_bf16(
            frag_from(af[1]), bf, acc[1][nt], 0, 0, 0);
      }
    }
  }
  // write num partial (coalesced over l16)
#pragma unroll
  for (int mt = 0; mt < 2; ++mt)
#pragma unroll
    for (int nt = 0; nt < 8; ++nt)
#pragma unroll
      for (int r = 0; r < 4; ++r) {
        int h = mt * 16 + quad * 4 + r;
        int l = wave * 128 + nt * 16 + l16;
        num_part[((size_t)wg * 32 + h) * 512 + l] = acc[mt][nt][r];
      }
  // den partial: reduce over 16 kv lanes, combine kv-halves via LDS
  float dv[4];
#pragma unroll
  for (int r = 0; r < 4; ++r) {
    float v = den_acc[r];
    v += __shfl_xor(v, 1, 64);
    v += __shfl_xor(v, 2, 64);
    v += __shfl_xor(v, 4, 64);
    v += __shfl_xor(v, 8, 64);
    dv[r] = v;
  }
  if (l16 == 0) {
#pragma unroll
    for (int r = 0; r < 4; ++r)
      den_sh[kvh][hh * 16 + quad * 4 + r] = dv[r];
  }
  __syncthreads();
  if (t < 32) den_part[wg * 32 + t] = den_sh[0][t] + den_sh[1][t];
}

// --------------------------------------------- K4: reduce + divide + W_UV
// grid (16 l-chunks of 32, 32 heads) = 512 blocks, float4 num_part reads.
__global__ __launch_bounds__(256) void k4_reduce_wuv(
    const float* __restrict__ num_part, const float* __restrict__ den_part,
    const float* __restrict__ W_UV, float* __restrict__ o_acc) {
  __shared__ float attn[32][33];
  __shared__ float den[32];
  const int t = threadIdx.x;
  const int lc = blockIdx.x, h = blockIdx.y;
  const int c0 = lc * 32;
  if (t < 32) {
    float s = 0.f;
    for (int p = 0; p < 16; ++p) s += den_part[(t * 16 + p) * 32 + h];
    den[t] = s;
  }
  __syncthreads();
  {
    const int b = t >> 3, l4 = (t & 7) * 4;   // 32 b x 8 l-quads
    float4 s = {0.f, 0.f, 0.f, 0.f};
#pragma unroll
    for (int p = 0; p < 16; ++p) {
      float4 v = *(const float4*)&num_part[((size_t)(b * 16 + p) * 32 + h) * 512 + c0 + l4];
      s.x += v.x; s.y += v.y; s.z += v.z; s.w += v.w;
    }
    float inv = 1.f / den[b];
    attn[b][l4 + 0] = s.x * inv;
    attn[b][l4 + 1] = s.y * inv;
    attn[b][l4 + 2] = s.z * inv;
    attn[b][l4 + 3] = s.w * inv;
  }
  __syncthreads();
  const int v = t & 127, rg = t >> 7;
  float acc[16];
#pragma unroll
  for (int r = 0; r < 16; ++r) acc[r] = 0.f;
  for (int l = 0; l < 32; ++l) {
    float w = W_UV[(h * 512 + c0 + l) * 128 + v];
#pragma unroll
    for (int r = 0; r < 16; ++r) acc[r] += attn[rg * 16 + r][l] * w;
  }
  for (int r = 0; r < 16; ++r)
    atomicAdd(&o_acc[(size_t)(rg * 16 + r) * 4096 + h * 128 + v], acc[r]);
}

// -------------------------------------------------------- K5: o @ W_O
// grid (16 k-splits of 256, 40 n-tiles of 128), bf16 MFMA, float4 staging,
// atomicAdd into zeroed out.
__global__ __launch_bounds__(256) void k5_wo(
    const float* __restrict__ o_acc, const float* __restrict__ W_O,
    float* __restrict__ out) {
  __shared__ uint32_t Bt[32 * 130];  // k-pair-zip of a 64k x 128n W_O chunk
  const int t = threadIdx.x;
  const int ksplit = blockIdx.x, ntile = blockIdx.y;
  const int n0 = ntile * 128, kbase = ksplit * 256;
  const int wave = t >> 6, lane = t & 63, quad = lane >> 4, l16 = lane & 15;
  const f32x4 fzero = {0.f, 0.f, 0.f, 0.f};
  f32x4 acc[2][2];
#pragma unroll
  for (int mt = 0; mt < 2; ++mt)
#pragma unroll
    for (int nt = 0; nt < 2; ++nt) acc[mt][nt] = fzero;
  for (int kc = 0; kc < 4; ++kc) {
    const int k0 = kbase + kc * 64;
    __syncthreads();
    for (int idx = t; idx < 1024; idx += 256) {  // k2 in [0,32) x c4 in [0,32)
      int k2 = idx >> 5, c4 = idx & 31;
      const float* p0 = &W_O[(size_t)(k0 + 2 * k2) * 5120 + n0 + c4 * 4];
      float4 a = *(const float4*)p0;
      float4 b = *(const float4*)(p0 + 5120);
      uint32_t* bp = &Bt[k2 * 130 + c4 * 4];
      bp[0] = pack2bf(a.x, b.x);
      bp[1] = pack2bf(a.y, b.y);
      bp[2] = pack2bf(a.z, b.z);
      bp[3] = pack2bf(a.w, b.w);
    }
    __syncthreads();
#pragma unroll
    for (int ks2 = 0; ks2 < 2; ++ks2) {
      uint32_t af[2][4];
#pragma unroll
      for (int mt = 0; mt < 2; ++mt) {
        const float* orow =
            o_acc + (size_t)(mt * 16 + l16) * 4096 + k0 + ks2 * 32 + quad * 8;
        float4 x = *(const float4*)orow;
        float4 y = *(const float4*)(orow + 4);
        af[mt][0] = pack2bf(x.x, x.y);
        af[mt][1] = pack2bf(x.z, x.w);
        af[mt][2] = pack2bf(y.x, y.y);
        af[mt][3] = pack2bf(y.z, y.w);
      }
#pragma unroll
      for (int nt = 0; nt < 2; ++nt) {
        uint32_t br[4];
#pragma unroll
        for (int i = 0; i < 4; ++i)
          br[i] = Bt[(ks2 * 16 + quad * 4 + i) * 130 + wave * 32 + nt * 16 + l16];
        short8 bf = frag_from(br);
        acc[0][nt] = __builtin_amdgcn_mfma_f32_16x16x32_bf16(
            frag_from(af[0]), bf, acc[0][nt], 0, 0, 0);
        acc[1][nt] = __builtin_amdgcn_mfma_f32_16x16x32_bf16(
            frag_from(af[1]), bf, acc[1][nt], 0, 0, 0);
      }
    }
  }
#pragma unroll
  for (int mt = 0; mt < 2; ++mt)
#pragma unroll
    for (int nt = 0; nt < 2; ++nt)
#pragma unroll
      for (int r = 0; r < 4; ++r) {
        int b = mt * 16 + quad * 4 + r;
        int c = n0 + wave * 32 + nt * 16 + l16;
        atomicAdd(&out[(size_t)b * 5120 + c], acc[mt][nt][r]);
      }
}

extern "C" void kernel_launch(void* const* d_in, const int* in_sizes, int n_in,
                              void* d_out, int out_size, void* d_ws,
                              size_t ws_size, hipStream_t stream) {
  (void)in_sizes; (void)n_in; (void)ws_size;
  const float* hidden = (const float*)d_in[0];
  const float* k_c    = (const float*)d_in[1];
  const float* k_pe   = (const float*)d_in[2];
  float* cache_k      = (float*)d_in[3];
  float* cache_v      = (float*)d_in[4];
  const float* W_Q    = (const float*)d_in[5];
  const float* W_UK   = (const float*)d_in[6];
  const float* W_QR   = (const float*)d_in[7];
  const float* W_UV   = (const float*)d_in[8];
  const float* W_O    = (const float*)d_in[9];
  const int* ipos     = (const int*)d_in[10];
  const int* blist    = (const int*)d_in[11];
  const int* bgroups  = (const int*)d_in[12];
  const float* bbias  = (const float*)d_in[13];
  const int* bindices = (const int*)d_in[14];
  const int* boffsets = (const int*)d_in[15];

  char* ws = (char*)d_ws;
  float*    q_nope0  = (float*)(ws);                 //   524288 B
  float*    q_pe0    = (float*)(ws + 524288);        //   262144 B
  float*    o_acc    = (float*)(ws + 786432);        //   524288 B
  uint16_t* q_bf     = (uint16_t*)(ws + 1310720);    //  1179648 B
  float*    den_part = (float*)(ws + 2490368);       //    65536 B
  float*    num_part = (float*)(ws + 2555904);       // 33554432 B  (36.1 MB total)
  // q_acc (2 MB, fp32 32x32x512) aliases num_part: dead before k3 writes it.
  float*    q_acc    = num_part;
  float*    out      = (float*)d_out;

  hipMemsetAsync(ws, 0, 1310720, stream);            // q_nope0, q_pe0, o_acc
  hipMemsetAsync((void*)q_acc, 0, 2097152, stream);  // q_acc (atomic target)
  hipMemsetAsync(d_out, 0, (size_t)out_size * sizeof(float), stream);

  k1_qproj<<<dim3(48, 12), 256, 0, stream>>>(hidden, W_Q, W_QR, q_nope0, q_pe0);
  k2_qlora<<<dim3(4, 32, 4), 256, 0, stream>>>(q_nope0, W_UK, q_acc);
  k2b_rope_scatter<<<dim3(32, 8), 256, 0, stream>>>(q_pe0, k_pe, k_c, ipos,
                                                    bindices, boffsets, q_acc,
                                                    cache_k, cache_v, q_bf);
  k3_attn<<<dim3(16, 32), 256, 0, stream>>>(q_bf, cache_k, cache_v, blist,
                                            bgroups, bbias, num_part, den_part);
  k4_reduce_wuv<<<dim3(16, 32), 256, 0, stream>>>(num_part, den_part, W_UV, o_acc);
  k5_wo<<<dim3(16, 40), 256, 0, stream>>>(o_acc, W_O, out);
}

// Round 4
// 693.190 us; speedup vs baseline: 1.5049x; 1.0133x over previous
//
#include <hip/hip_runtime.h>
#include <hip/hip_bf16.h>
#include <stdint.h>

// MLA decode: B=32, H=32, KV_LORA=512, ROPE=64, NOPE=128, VH=128, QL=1536,
// HID=5120, BLK=128, 32 blocks/seq, NB=1024. fp32 in/out, bf16 MFMA internals.
// R4: num_part (33.5 MB round-trip) replaced by atomic num_acc (4 MB, L2);
//     k3 staging de-divided; k4 rebuilt. ~60 MB HBM traffic removed.

typedef __attribute__((ext_vector_type(8))) short short8;
typedef __attribute__((ext_vector_type(4))) float f32x4;

__device__ inline uint32_t f2bf(float f) {
  uint32_t u = __float_as_uint(f);
  return (u + 0x7fffu + ((u >> 16) & 1u)) >> 16;   // RNE
}
// packed f32x2 -> bf16x2 via v_cvt_pk_bf16_f32 (gfx950)
union Bf2U { __hip_bfloat162 h; uint32_t u; };
__device__ inline uint32_t pack2bf(float lo, float hi) {
  Bf2U v; v.h = __float22bfloat162_rn(float2{lo, hi});
  return v.u;
}
union FragU { uint32_t u[4]; short8 s; };
__device__ inline short8 frag_from(const uint32_t r[4]) {
  FragU v; v.u[0] = r[0]; v.u[1] = r[1]; v.u[2] = r[2]; v.u[3] = r[3];
  return v.s;
}

// ---------------------------------------------------------------- K1: q proj
// out[b][c] = sum_k hidden[b][k] * W[k][c], W = [W_Q (4096 cols) | W_QR (2048)]
// grid (48 col-tiles of 128, 12 k-splits of 128) = 576 blocks (2.25/CU).
__global__ __launch_bounds__(256) void k1_qproj(
    const float* __restrict__ hidden, const float* __restrict__ W_Q,
    const float* __restrict__ W_QR, float* __restrict__ q_nope0,
    float* __restrict__ q_pe0) {
  __shared__ float hl[32][129];
  const int t = threadIdx.x;
  const int ctile = blockIdx.x * 128;
  const int k0 = blockIdx.y * 128;
  const bool isQ = (ctile < 4096);
  const float* W = isQ ? W_Q : W_QR;
  const int wstride = isQ ? 4096 : 2048;
  const int c = (isQ ? ctile : ctile - 4096) + (t & 31) * 4;
  const int rg = t >> 5;  // 8 groups x 4 batch rows
  for (int idx = t; idx < 4096; idx += 256) {
    int b = idx >> 7, kk = idx & 127;
    hl[b][kk] = hidden[b * 1536 + k0 + kk];
  }
  __syncthreads();
  float acc[4][4];
#pragma unroll
  for (int r = 0; r < 4; ++r)
#pragma unroll
    for (int j = 0; j < 4; ++j) acc[r][j] = 0.f;
  const float* wp = W + (size_t)k0 * wstride + c;
#pragma unroll 4
  for (int kk = 0; kk < 128; ++kk) {
    float4 w = *(const float4*)wp;
    wp += wstride;
#pragma unroll
    for (int r = 0; r < 4; ++r) {
      float hv = hl[rg * 4 + r][kk];
      acc[r][0] += hv * w.x;
      acc[r][1] += hv * w.y;
      acc[r][2] += hv * w.z;
      acc[r][3] += hv * w.w;
    }
  }
  float* dst = isQ ? q_nope0 : q_pe0;
#pragma unroll
  for (int r = 0; r < 4; ++r)
#pragma unroll
    for (int j = 0; j < 4; ++j)
      atomicAdd(&dst[(rg * 4 + r) * wstride + c + j], acc[r][j]);
}

// --------------------------------------------------------------- K2: q_lora
// q_acc[b][h][c] += sum_d q_nope0[b][h*128+d] * W_UK[h][d][c]  (fp32 atomics)
// grid (4 c-tiles of 128, 32 heads, 4 d-splits of 32) = 512 blocks (2/CU).
__global__ __launch_bounds__(256) void k2_qlora(
    const float* __restrict__ q_nope0, const float* __restrict__ W_UK,
    float* __restrict__ q_acc) {
  __shared__ float qn[32][33];
  const int t = threadIdx.x;
  const int h = blockIdx.y;
  const int c0 = blockIdx.x * 128;
  const int d0 = blockIdx.z * 32;
  for (int idx = t; idx < 1024; idx += 256) {
    int b = idx >> 5, dd = idx & 31;
    qn[b][dd] = q_nope0[b * 4096 + h * 128 + d0 + dd];
  }
  __syncthreads();
  const int c = c0 + (t & 31) * 4;
  const int rg = t >> 5;  // 8 groups x 4 batch rows
  float acc[4][4];
#pragma unroll
  for (int r = 0; r < 4; ++r)
#pragma unroll
    for (int j = 0; j < 4; ++j) acc[r][j] = 0.f;
  const float* wp = W_UK + (size_t)(h * 128 + d0) * 512 + c;
#pragma unroll 4
  for (int dd = 0; dd < 32; ++dd) {
    float4 w = *(const float4*)wp;
    wp += 512;
#pragma unroll
    for (int r = 0; r < 4; ++r) {
      float qv = qn[rg * 4 + r][dd];
      acc[r][0] += qv * w.x;
      acc[r][1] += qv * w.y;
      acc[r][2] += qv * w.z;
      acc[r][3] += qv * w.w;
    }
  }
#pragma unroll
  for (int r = 0; r < 4; ++r)
#pragma unroll
    for (int j = 0; j < 4; ++j)
      atomicAdd(&q_acc[(size_t)((rg * 4 + r) * 32 + h) * 512 + c + j],
                acc[r][j]);
}

// ------------------------- K2b: RoPE + cache scatter + q_acc->bf16 convert
// grid (32 seqs, 8 head-slices of 4) = 256 blocks.
__global__ __launch_bounds__(256) void k2b_rope_scatter(
    const float* __restrict__ q_pe0, const float* __restrict__ k_pe,
    const float* __restrict__ k_c_normed, const int* __restrict__ ipos,
    const int* __restrict__ bindices, const int* __restrict__ boffsets,
    const float* __restrict__ q_acc, float* __restrict__ cache_k,
    float* __restrict__ cache_v, uint16_t* __restrict__ q_bf) {
  const int b = blockIdx.x;
  const int hs = blockIdx.y * 4;   // 4 heads per block
  const int t = threadIdx.x;
  const float pos = (float)ipos[b];
  const float scale = 0.07216878364870323f;  // 1/sqrt(192)
  const float lnk = 0.28782313662425575f;    // ln(10000)/32
  // nope part: scale + convert (4 heads x 512 c)
  for (int idx = t; idx < 2048; idx += 256) {
    int h = hs + (idx >> 9), c = idx & 511;
    q_bf[((size_t)b * 32 + h) * 576 + c] =
        (uint16_t)f2bf(q_acc[((size_t)b * 32 + h) * 512 + c] * scale);
  }
  // rope part of q (4 heads x 32 pairs)
  if (t < 128) {
    int h = hs + (t >> 5), i = t & 31;
    float ang = pos * __expf(-(float)i * lnk);
    float s, c;
    sincosf(ang, &s, &c);
    float x1 = q_pe0[b * 2048 + h * 64 + i];
    float x2 = q_pe0[b * 2048 + h * 64 + 32 + i];
    int base = (b * 32 + h) * 576 + 512;
    q_bf[base + i]      = (uint16_t)f2bf((x1 * c - x2 * s) * scale);
    q_bf[base + 32 + i] = (uint16_t)f2bf((x2 * c + x1 * s) * scale);
  }
  if (blockIdx.y == 0) {
    const int row = bindices[b] * 128 + boffsets[b];
    if (t < 32) {
      int i = t;
      float ang = pos * __expf(-(float)i * lnk);
      float s, c;
      sincosf(ang, &s, &c);
      float x1 = k_pe[b * 64 + i], x2 = k_pe[b * 64 + 32 + i];
      cache_k[row * 64 + i]      = x1 * c - x2 * s;
      cache_k[row * 64 + 32 + i] = x2 * c + x1 * s;
    }
    for (int j = t; j < 512; j += 256)
      cache_v[row * 512 + j] = k_c_normed[b * 512 + j];
  }
}

// ------------------------------------------------------------ K3: attention
// grid (16 parts, 32 seqs), 256 thr (4 waves), 2 blocks/WG, 32-kv sub-tiles.
// LDS tile Tl: d-pair-zip  Tl[d2*33+kv] = {T[kv][2d2], T[kv][2d2+1]} (bf16 pair)
// Partial num/den accumulated straight into global num_acc/den_acc (atomics,
// L2-resident) -- no 33.5 MB num_part round-trip.
__global__ __launch_bounds__(256, 2) void k3_attn(
    const uint16_t* __restrict__ q_bf, const float* __restrict__ cache_k,
    const float* __restrict__ cache_v, const int* __restrict__ block_list,
    const int* __restrict__ block_groups, const float* __restrict__ block_bias,
    float* __restrict__ num_acc, float* __restrict__ den_acc) {
  __shared__ uint32_t Tl[288 * 33];
  __shared__ uint32_t Pl[16 * 33];
  __shared__ float den_sh[2][32];

  const int t = threadIdx.x;
  const int part = blockIdx.x, bseq = blockIdx.y;
  const int wave = t >> 6, lane = t & 63, quad = lane >> 4, l16 = lane & 15;
  const int hh = wave >> 1, kvh = wave & 1;
  const int n0 = bseq * 32 + part * 2;
  const int g = block_groups[n0];

  // Q fragments (this wave's 16-head half), 72 dwords in registers
  uint32_t qf[72];
  {
    const uint32_t* qrow =
        (const uint32_t*)(q_bf + (size_t)(g * 32 + hh * 16 + l16) * 576);
#pragma unroll
    for (int ks = 0; ks < 18; ++ks)
#pragma unroll
      for (int i = 0; i < 4; ++i)
        qf[ks * 4 + i] = qrow[ks * 16 + quad * 4 + i];
  }

  const f32x4 fzero = {0.f, 0.f, 0.f, 0.f};
  f32x4 acc[2][8];
#pragma unroll
  for (int mt = 0; mt < 2; ++mt)
#pragma unroll
    for (int nt = 0; nt < 8; ++nt) acc[mt][nt] = fzero;
  float den_acc_r[4] = {0.f, 0.f, 0.f, 0.f};

  for (int blk_i = 0; blk_i < 2; ++blk_i) {
    const int n = n0 + blk_i;
    const int phys = block_list[n];
    const float* vrow = cache_v + (size_t)phys * 128 * 512;
    const float* krow = cache_k + (size_t)phys * 128 * 64;
    for (int s = 0; s < 4; ++s) {
      const int s0 = s * 32;
      __syncthreads();  // previous PV readers done
      // stage V: 32 kv x 512 d = 4096 float4 (no divide, no branch)
#pragma unroll
      for (int i = 0; i < 16; ++i) {
        int idx = i * 256 + t;
        int kv = idx >> 7, f4 = idx & 127;
        float4 v = *(const float4*)(vrow + (s0 + kv) * 512 + f4 * 4);
        int d2 = f4 * 2;
        Tl[(d2    ) * 33 + kv] = pack2bf(v.x, v.y);
        Tl[(d2 + 1) * 33 + kv] = pack2bf(v.z, v.w);
      }
      // stage K: 32 kv x 64 d = 512 float4
#pragma unroll
      for (int i = 0; i < 2; ++i) {
        int idx = i * 256 + t;
        int kv = idx >> 4, f4 = idx & 15;
        float4 v = *(const float4*)(krow + (s0 + kv) * 64 + f4 * 4);
        int d2 = 256 + f4 * 2;
        Tl[(d2    ) * 33 + kv] = pack2bf(v.x, v.y);
        Tl[(d2 + 1) * 33 + kv] = pack2bf(v.z, v.w);
      }
      __syncthreads();
      // ---- logits: wave computes 16h x 16kv tile (hh, kvh), K = 576
      const int tkv = kvh * 16 + l16;
      f32x4 lg = fzero;
#pragma unroll
      for (int ks = 0; ks < 18; ++ks) {
        uint32_t br[4];
#pragma unroll
        for (int i = 0; i < 4; ++i)
          br[i] = Tl[(ks * 16 + quad * 4 + i) * 33 + tkv];
        lg = __builtin_amdgcn_mfma_f32_16x16x32_bf16(
            frag_from(&qf[ks * 4]), frag_from(br), lg, 0, 0, 0);
      }
      float bias = block_bias[n * 128 + s0 + tkv];
      uint32_t pb[4];
#pragma unroll
      for (int r = 0; r < 4; ++r) {
        float p = __expf(lg[r] + bias);   // no shift: |logit| <= ~9, safe
        pb[r] = f2bf(p);
        den_acc_r[r] += __uint_as_float(pb[r] << 16);
      }
#pragma unroll
      for (int r = 0; r < 4; ++r) {       // kv-pair-zip P into LDS
        uint32_t other = (uint32_t)__shfl_xor((int)pb[r], 1, 64);
        if ((l16 & 1) == 0) {
          int h = hh * 16 + quad * 4 + r;
          Pl[(tkv >> 1) * 33 + h] = pb[r] | (other << 16);
        }
      }
      __syncthreads();
      // ---- PV: wave handles l-slice [wave*128, wave*128+128)
      uint32_t af[2][4];
#pragma unroll
      for (int mt = 0; mt < 2; ++mt)
#pragma unroll
        for (int i = 0; i < 4; ++i)
          af[mt][i] = Pl[(quad * 4 + i) * 33 + mt * 16 + l16];
#pragma unroll
      for (int nt = 0; nt < 8; ++nt) {
        int l = wave * 128 + nt * 16 + l16;
        const uint32_t* base = &Tl[(l >> 1) * 33 + quad * 8];
        uint32_t dw[8];
#pragma unroll
        for (int j = 0; j < 8; ++j) dw[j] = base[j];
        uint32_t br[4];
        const bool odd = (l & 1);
#pragma unroll
        for (int i = 0; i < 4; ++i) {
          uint32_t a = dw[2 * i], bq = dw[2 * i + 1];
          uint32_t lo = odd ? (a >> 16) : (a & 0xffffu);
          uint32_t hi = odd ? (bq & 0xffff0000u) : (bq << 16);
          br[i] = lo | hi;
        }
        short8 bf = frag_from(br);
        acc[0][nt] = __builtin_amdgcn_mfma_f32_16x16x32_bf16(
            frag_from(af[0]), bf, acc[0][nt], 0, 0, 0);
        acc[1][nt] = __builtin_amdgcn_mfma_f32_16x16x32_bf16(
            frag_from(af[1]), bf, acc[1][nt], 0, 0, 0);
      }
    }
  }
  // accumulate num partial straight into global (coalesced over l16)
#pragma unroll
  for (int mt = 0; mt < 2; ++mt)
#pragma unroll
    for (int nt = 0; nt < 8; ++nt)
#pragma unroll
      for (int r = 0; r < 4; ++r) {
        int h = mt * 16 + quad * 4 + r;
        int l = wave * 128 + nt * 16 + l16;
        atomicAdd(&num_acc[((size_t)(g * 32 + h)) * 512 + l], acc[mt][nt][r]);
      }
  // den partial: reduce over 16 kv lanes, combine kv-halves via LDS
  float dv[4];
#pragma unroll
  for (int r = 0; r < 4; ++r) {
    float v = den_acc_r[r];
    v += __shfl_xor(v, 1, 64);
    v += __shfl_xor(v, 2, 64);
    v += __shfl_xor(v, 4, 64);
    v += __shfl_xor(v, 8, 64);
    dv[r] = v;
  }
  if (l16 == 0) {
#pragma unroll
    for (int r = 0; r < 4; ++r)
      den_sh[kvh][hh * 16 + quad * 4 + r] = dv[r];
  }
  __syncthreads();
  if (t < 32) atomicAdd(&den_acc[g * 32 + t], den_sh[0][t] + den_sh[1][t]);
}

// --------------------------------------------- K4: divide + W_UV
// grid (8 l-chunks of 64, 32 heads) = 256 blocks.
__global__ __launch_bounds__(256) void k4_reduce_wuv(
    const float* __restrict__ num_acc, const float* __restrict__ den_acc,
    const float* __restrict__ W_UV, float* __restrict__ o_acc) {
  __shared__ float attn[32][65];
  __shared__ float inv[32];
  const int t = threadIdx.x;
  const int l0 = blockIdx.x * 64;
  const int h = blockIdx.y;
  if (t < 32) inv[t] = 1.f / den_acc[t * 32 + h];
  __syncthreads();
  for (int idx = t; idx < 2048; idx += 256) {
    int b = idx >> 6, l = idx & 63;
    attn[b][l] = num_acc[((size_t)(b * 32 + h)) * 512 + l0 + l] * inv[b];
  }
  __syncthreads();
  const int v = t & 127, rg = t >> 7;
  float acc[16];
#pragma unroll
  for (int r = 0; r < 16; ++r) acc[r] = 0.f;
  const float* wp = W_UV + ((size_t)h * 512 + l0) * 128 + v;
#pragma unroll 4
  for (int l = 0; l < 64; ++l) {
    float w = *wp;
    wp += 128;
#pragma unroll
    for (int r = 0; r < 16; ++r) acc[r] += attn[rg * 16 + r][l] * w;
  }
#pragma unroll
  for (int r = 0; r < 16; ++r)
    atomicAdd(&o_acc[(size_t)(rg * 16 + r) * 4096 + h * 128 + v], acc[r]);
}

// -------------------------------------------------------- K5: o @ W_O
// grid (16 k-splits of 256, 40 n-tiles of 128), bf16 MFMA, float4 staging,
// atomicAdd into zeroed out.
__global__ __launch_bounds__(256) void k5_wo(
    const float* __restrict__ o_acc, const float* __restrict__ W_O,
    float* __restrict__ out) {
  __shared__ uint32_t Bt[32 * 130];  // k-pair-zip of a 64k x 128n W_O chunk
  const int t = threadIdx.x;
  const int ksplit = blockIdx.x, ntile = blockIdx.y;
  const int n0 = ntile * 128, kbase = ksplit * 256;
  const int wave = t >> 6, lane = t & 63, quad = lane >> 4, l16 = lane & 15;
  const f32x4 fzero = {0.f, 0.f, 0.f, 0.f};
  f32x4 acc[2][2];
#pragma unroll
  for (int mt = 0; mt < 2; ++mt)
#pragma unroll
    for (int nt = 0; nt < 2; ++nt) acc[mt][nt] = fzero;
  for (int kc = 0; kc < 4; ++kc) {
    const int k0 = kbase + kc * 64;
    __syncthreads();
    for (int idx = t; idx < 1024; idx += 256) {  // k2 in [0,32) x c4 in [0,32)
      int k2 = idx >> 5, c4 = idx & 31;
      const float* p0 = &W_O[(size_t)(k0 + 2 * k2) * 5120 + n0 + c4 * 4];
      float4 a = *(const float4*)p0;
      float4 b = *(const float4*)(p0 + 5120);
      uint32_t* bp = &Bt[k2 * 130 + c4 * 4];
      bp[0] = pack2bf(a.x, b.x);
      bp[1] = pack2bf(a.y, b.y);
      bp[2] = pack2bf(a.z, b.z);
      bp[3] = pack2bf(a.w, b.w);
    }
    __syncthreads();
#pragma unroll
    for (int ks2 = 0; ks2 < 2; ++ks2) {
      uint32_t af[2][4];
#pragma unroll
      for (int mt = 0; mt < 2; ++mt) {
        const float* orow =
            o_acc + (size_t)(mt * 16 + l16) * 4096 + k0 + ks2 * 32 + quad * 8;
        float4 x = *(const float4*)orow;
        float4 y = *(const float4*)(orow + 4);
        af[mt][0] = pack2bf(x.x, x.y);
        af[mt][1] = pack2bf(x.z, x.w);
        af[mt][2] = pack2bf(y.x, y.y);
        af[mt][3] = pack2bf(y.z, y.w);
      }
#pragma unroll
      for (int nt = 0; nt < 2; ++nt) {
        uint32_t br[4];
#pragma unroll
        for (int i = 0; i < 4; ++i)
          br[i] = Bt[(ks2 * 16 + quad * 4 + i) * 130 + wave * 32 + nt * 16 + l16];
        short8 bf = frag_from(br);
        acc[0][nt] = __builtin_amdgcn_mfma_f32_16x16x32_bf16(
            frag_from(af[0]), bf, acc[0][nt], 0, 0, 0);
        acc[1][nt] = __builtin_amdgcn_mfma_f32_16x16x32_bf16(
            frag_from(af[1]), bf, acc[1][nt], 0, 0, 0);
      }
    }
  }
#pragma unroll
  for (int mt = 0; mt < 2; ++mt)
#pragma unroll
    for (int nt = 0; nt < 2; ++nt)
#pragma unroll
      for (int r = 0; r < 4; ++r) {
        int b = mt * 16 + quad * 4 + r;
        int c = n0 + wave * 32 + nt * 16 + l16;
        atomicAdd(&out[(size_t)b * 5120 + c], acc[mt][nt][r]);
      }
}

extern "C" void kernel_launch(void* const* d_in, const int* in_sizes, int n_in,
                              void* d_out, int out_size, void* d_ws,
                              size_t ws_size, hipStream_t stream) {
  (void)in_sizes; (void)n_in; (void)ws_size;
  const float* hidden = (const float*)d_in[0];
  const float* k_c    = (const float*)d_in[1];
  const float* k_pe   = (const float*)d_in[2];
  float* cache_k      = (float*)d_in[3];
  float* cache_v      = (float*)d_in[4];
  const float* W_Q    = (const float*)d_in[5];
  const float* W_UK   = (const float*)d_in[6];
  const float* W_QR   = (const float*)d_in[7];
  const float* W_UV   = (const float*)d_in[8];
  const float* W_O    = (const float*)d_in[9];
  const int* ipos     = (const int*)d_in[10];
  const int* blist    = (const int*)d_in[11];
  const int* bgroups  = (const int*)d_in[12];
  const float* bbias  = (const float*)d_in[13];
  const int* bindices = (const int*)d_in[14];
  const int* boffsets = (const int*)d_in[15];

  char* ws = (char*)d_ws;
  float*    q_nope0  = (float*)(ws);                 //  524288 B (zeroed)
  float*    q_pe0    = (float*)(ws + 524288);        //  262144 B (zeroed)
  float*    o_acc    = (float*)(ws + 786432);        //  524288 B (zeroed)
  float*    q_acc    = (float*)(ws + 1310720);       // 2097152 B (zeroed)
  float*    num_acc  = (float*)(ws + 3407872);       // 4194304 B (zeroed)
  float*    den_acc  = (float*)(ws + 7602176);       //    4096 B (zeroed)
  uint16_t* q_bf     = (uint16_t*)(ws + 7606272);    // 1179648 B
  float*    out      = (float*)d_out;

  hipMemsetAsync(ws, 0, 7606272, stream);  // all atomic targets, one fill
  hipMemsetAsync(d_out, 0, (size_t)out_size * sizeof(float), stream);

  k1_qproj<<<dim3(48, 12), 256, 0, stream>>>(hidden, W_Q, W_QR, q_nope0, q_pe0);
  k2_qlora<<<dim3(4, 32, 4), 256, 0, stream>>>(q_nope0, W_UK, q_acc);
  k2b_rope_scatter<<<dim3(32, 8), 256, 0, stream>>>(q_pe0, k_pe, k_c, ipos,
                                                    bindices, boffsets, q_acc,
                                                    cache_k, cache_v, q_bf);
  k3_attn<<<dim3(16, 32), 256, 0, stream>>>(q_bf, cache_k, cache_v, blist,
                                            bgroups, bbias, num_acc, den_acc);
  k4_reduce_wuv<<<dim3(8, 32), 256, 0, stream>>>(num_acc, den_acc, W_UV, o_acc);
  k5_wo<<<dim3(16, 40), 256, 0, stream>>>(o_acc, W_O, out);
}